// Round 14
// baseline (81.739 us; speedup 1.0000x reference)
//
#include <hip/hip_runtime.h>
#include <cstdint>

#pragma clang fp contract(off)

#define R_N   2000
#define C1    21
#define NCLS  20
#define MAXFV 512
#define OUT_LBL   200000
#define OUT_KEEP  240000
#define FMARGIN   4.0f      // |inter-0.3uni| f32 err bound ~0.5 px^2; 4.0 = big safety

// wave-level LDS drain: orders this wave's ds ops; windows are wave-private
#define WAVE_SYNC() do {                                        \
  __builtin_amdgcn_sched_barrier(0);                            \
  asm volatile("s_waitcnt lgkmcnt(0)" ::: "memory");            \
  __builtin_amdgcn_sched_barrier(0);                            \
} while (0)

__device__ __forceinline__ double read_dim(const void* p) {
  int iv = *(const int*)p;
  if (iv >= 1 && iv <= 1000000) return (double)iv;
  float fv = *(const float*)p;
  if (fv >= 1.0f && fv <= 1000000.0f) return (double)fv;
  return *(const double*)p;
}

// ---- K1: wide decode + softmax + output zeroing + flag reset ----
__global__ __launch_bounds__(256) void prep3_kernel(
    const float* __restrict__ rois, const float* __restrict__ loc,
    const float* __restrict__ score,
    const void* __restrict__ hptr, const void* __restrict__ wptr,
    double4* __restrict__ dbox_all, double* __restrict__ prob_t,
    float* __restrict__ out, int* __restrict__ flags)
{
  int tid = blockIdx.x * 256 + threadIdx.x;
  // zero the whole output (280000 f32 = 70000 float4); scan writes only kept rows
  float4 z4 = make_float4(0.f, 0.f, 0.f, 0.f);
  for (int z = tid; z < 70000; z += 168 * 256) ((float4*)out)[z] = z4;

  if (tid < 40000) {
    int r = tid % R_N, c = tid / R_N;
    const double H = read_dim(hptr), W = read_dim(wptr);
    const float* l4 = loc + r * 84 + (c + 1) * 4;
    double dy = (double)l4[0], dx = (double)l4[1];
    double eh = exp((double)l4[2]), ew = exp((double)l4[3]);
    double b0 = (double)rois[r*4+0], b1 = (double)rois[r*4+1];
    double b2 = (double)rois[r*4+2], b3 = (double)rois[r*4+3];
    double sh  = b2 - b0,       sw  = b3 - b1;
    double scy = b0 + 0.5*sh,   scx = b1 + 0.5*sw;
    double cy = dy*sh + scy,    cx = dx*sw + scx;
    double hh = eh*sh,          ww = ew*sw;
    double y1 = fmin(fmax(cy - 0.5*hh, 0.0), H);
    double x1 = fmin(fmax(cx - 0.5*ww, 0.0), W);
    double y2 = fmin(fmax(cy + 0.5*hh, 0.0), H);
    double x2 = fmin(fmax(cx + 0.5*ww, 0.0), W);
    dbox_all[c * R_N + r] = make_double4(y1, x1, y2, x2);
  } else if (tid >= 40960 && tid < 40960 + R_N) {
    int r = tid - 40960;
    const float* sc = score + r * C1;
    double m = (double)sc[0];
    #pragma unroll
    for (int k = 1; k < C1; ++k) m = fmax(m, (double)sc[k]);
    double e[C1]; double s = 0.0;
    #pragma unroll
    for (int k = 0; k < C1; ++k) { e[k] = exp((double)sc[k] - m); s += e[k]; }
    #pragma unroll
    for (int c = 0; c < NCLS; ++c) prob_t[c * R_N + r] = e[c + 1] / s;
  } else if (tid >= 42960 && tid < 43000) {
    flags[tid - 42960] = 0;             // ready[20] | done[20]
  }
}

// ---- K2 (merged): per-class sort+export -> signal -> 9 build blocks -> scan ----
__global__ __launch_bounds__(256) void nmspipe_kernel(
    float* __restrict__ out,
    const double4* __restrict__ dbox_all, const double* __restrict__ prob_t,
    float4* __restrict__ fbox4, double4* __restrict__ dbox4s,
    float* __restrict__ farea, float* __restrict__ sprobg,
    int* __restrict__ vcls, unsigned long long* __restrict__ kw,
    int* __restrict__ ready, int* __restrict__ done)
{
  __shared__ double sbd[R_N][4];          // fallback only (V>MAXFV)
  __shared__ ulonglong2 keys[2048];       // sort buffer; later overlaid as ckill in scan
  __shared__ double klist64[2][64][5];
  __shared__ float  klist32[2][64][5];
  __shared__ unsigned long long keptm[8];
  __shared__ int kcnt[2];
  __shared__ int wsum[4];

  const int cls = blockIdx.x;
  const int t = threadIdx.x;
  const int lane = t & 63, wid = t >> 6;

  if (blockIdx.y != 0) {
    // ================== build path (9 blocks/class) ==================
    if (t == 0) {
      while (__hip_atomic_load(&ready[cls], __ATOMIC_ACQUIRE,
                               __HIP_MEMORY_SCOPE_AGENT) == 0)
        __builtin_amdgcn_s_sleep(8);
    }
    __syncthreads();
    const int V = vcls[cls];
    if (V <= MAXFV) {
      int n = (blockIdx.y - 1) * 256 + t;     // 0..2303 (same mapping as proven build)
      int c = 0;
      #pragma unroll
      for (int cc = 1; cc < 8; ++cc) if (n >= 32*cc*(cc+1)) c = cc;
      int rem = n - 32*c*(c+1);
      int jq = rem / (c + 1);
      int j = 64*c + jq;
      int w = rem - jq*(c+1);
      if (j < V) {
        const float4* fb = fbox4 + cls * MAXFV;
        const float*  fa = farea + cls * MAXFV;
        float4 mb = fb[j];
        float  ma = fa[j];
        int i0 = 64*w;
        int i1 = min(i0 + 64, j);
        unsigned long long acc = 0ull;
        #pragma unroll 8
        for (int i = i0; i < i1; ++i) {
          float4 bb = fb[i]; float ba = fa[i];
          float ty=fmaxf(bb.x,mb.x), tx=fmaxf(bb.y,mb.y);
          float by=fminf(bb.z,mb.z), bz=fminf(bb.w,mb.w);
          float w0=fmaxf(by-ty,0.f), w1=fmaxf(bz-tx,0.f);
          float inter=w0*w1;
          float uni=fmaxf(ba+ma-inter, 1e-9f);
          float rhs=0.3f*uni;
          bool kill = inter > rhs + FMARGIN;
          if (!kill && inter > rhs - FMARGIN) {   // rare: exact f64, reference op order
            double4 bd = dbox4s[cls*MAXFV + i];
            double4 md = dbox4s[cls*MAXFV + j];
            double bar=(bd.z-bd.x)*(bd.w-bd.y);
            double dar=(md.z-md.x)*(md.w-md.y);
            double ty_=fmax(bd.x,md.x), tx_=fmax(bd.y,md.y);
            double by_=fmin(bd.z,md.z), bz_=fmin(bd.w,md.w);
            double w0_=fmax(by_-ty_,0.0), w1_=fmax(bz_-tx_,0.0);
            double in_=w0_*w1_;
            double un_=bar+dar-in_;
            kill = in_/fmax(un_,1e-9) > 0.3;
          }
          acc |= (unsigned long long)(kill ? 1 : 0) << (i & 63);
        }
        kw[(size_t)(cls*MAXFV + j)*8 + w] = acc;
      }
    }
    __syncthreads();
    __threadfence();
    if (t == 0) atomicAdd(&done[cls], 1);
    return;
  }

  // ================== y==0: sort + export, then scan ==================
  // phase 1: probs -> keys
  ulonglong2 rk[8];
  int vmask = 0;
  #pragma unroll
  for (int u = 0; u < 8; ++u) {
    int r = t + 256 * u;
    rk[u] = make_ulonglong2(0ull, 0ull);
    if (r < R_N) {
      double p = prob_t[cls * R_N + r];
      if (p > 0.05) {
        rk[u] = make_ulonglong2((unsigned long long)__double_as_longlong(p),
                                (unsigned long long)(unsigned int)(~r));
        vmask |= 1 << u;
      }
    }
  }

  // phase 2: ballot-scan compaction
  int cnt = __popc(vmask);
  int x = cnt;
  #pragma unroll
  for (int off = 1; off < 64; off <<= 1) {
    int y = __shfl_up(x, off);
    if (lane >= off) x += y;
  }
  if (lane == 63) wsum[wid] = x;
  __syncthreads();
  int woff = 0;
  #pragma unroll
  for (int w2 = 0; w2 < 4; ++w2) { int s = wsum[w2]; if (w2 < wid) woff += s; }
  const int V = wsum[0] + wsum[1] + wsum[2] + wsum[3];
  int pos = woff + x - cnt;
  #pragma unroll
  for (int u = 0; u < 8; ++u)
    if ((vmask >> u) & 1) keys[pos++] = rk[u];

  int NSORT = 64; while (NSORT < V) NSORT <<= 1;
  for (int j = V + t; j < NSORT; j += 256)
    keys[j] = make_ulonglong2(0ull, (unsigned long long)(unsigned int)(~(unsigned)j));
  __syncthreads();

  // phase 3: bitonic sort (wave-local js<=64, block-wide js>=128) — proven R13
  const int wb = 128 * wid;
  int wsz = NSORT - wb; if (wsz > 128) wsz = 128;
  for (int k = 2; k <= NSORT; k <<= 1) {
    int js = k >> 1;
    if (js >= 128) {
      for (; js >= 128; js >>= 1) {
        __syncthreads();
        for (int p = t; p < (NSORT >> 1); p += 256) {
          int i = ((p & ~(js - 1)) << 1) | (p & (js - 1));
          int j = i | js;
          ulonglong2 a = keys[i], b = keys[j];
          bool altb = (a.x < b.x) || (a.x == b.x && a.y < b.y);
          if (altb == ((i & k) == 0)) { keys[i] = b; keys[j] = a; }
        }
      }
      __syncthreads();
    }
    if (wsz > 0) {
      for (; js > 0; js >>= 1) {
        if (lane < (wsz >> 1)) {
          int i = wb + (((lane & ~(js - 1)) << 1) | (lane & (js - 1)));
          int j = i | js;
          ulonglong2 a = keys[i], b = keys[j];
          bool altb = (a.x < b.x) || (a.x == b.x && a.y < b.y);
          if (altb == ((i & k) == 0)) { keys[i] = b; keys[j] = a; }
        }
        WAVE_SYNC();
      }
    }
  }
  __syncthreads();

  if (V <= MAXFV) {
    // export sorted slot arrays (proven)
    for (int j = t; j < V; j += 256) {
      ulonglong2 kj = keys[j];
      int idx = (int)(~(unsigned)kj.y);
      double4 bd = dbox_all[cls * R_N + idx];
      int g = cls * MAXFV + j;
      fbox4[g]  = make_float4((float)bd.x, (float)bd.y, (float)bd.z, (float)bd.w);
      dbox4s[g] = bd;
      farea[g]  = (float)((bd.z - bd.x) * (bd.w - bd.y));
      sprobg[g] = (float)__longlong_as_double((long long)kj.x);
    }
    __syncthreads();                    // all export stores issued
    __threadfence();
    if (t == 0) {
      vcls[cls] = V;
      __threadfence();
      __hip_atomic_store(&ready[cls], 1, __ATOMIC_RELEASE, __HIP_MEMORY_SCOPE_AGENT);
      // wait for the 9 build blocks
      while (__hip_atomic_load(&done[cls], __ATOMIC_ACQUIRE,
                               __HIP_MEMORY_SCOPE_AGENT) < 9)
        __builtin_amdgcn_s_sleep(8);
    }
    __syncthreads();

    // ===== scan (proven R13 body; ckill overlays keys LDS) =====
    unsigned long long (*ckill)[8][256] = (unsigned long long (*)[8][256])keys;
    unsigned long long ckq[2] = {0ull, 0ull};
    unsigned am = 0;
    #pragma unroll
    for (int q = 0; q < 2; ++q) {
      int j = t + 256*q;
      if (j < V) {
        am |= 1u << q;
        const unsigned long long* src = kw + (size_t)(cls*MAXFV + j)*8;
        int c = wid + 4*q;              // own chunk = j>>6 (wave-uniform)
        for (int w = 0; w < c; ++w) ckill[q][w][t] = src[w];
        ckq[q] = src[c];
      }
    }
    __syncthreads();

    unsigned km = 0;
    #pragma unroll
    for (int q = 0; q < 2; ++q) {
      if (256*q >= V) break;
      for (int sub = 0; sub < 4; ++sub) {
        const int ch = 4*q + sub;
        if (64*ch >= V) break;
        if (wid == sub) {
          bool a = ((am >> q) & 1u) != 0u;
          unsigned long long m = __ballot(a);
          unsigned long long kept = 0ull;
          while (m) {
            int i = __ffsll(m) - 1;
            unsigned long long bit = 1ull << i;
            kept |= bit; m &= ~bit;
            bool kill = ((ckq[q] >> i) & 1ull) != 0ull;
            m &= ~__ballot(kill);
          }
          am &= ~(1u << q);
          if ((kept >> lane) & 1ull) km |= 1u << q;
          if (lane == 0) keptm[ch] = kept;
        }
        __syncthreads();
        unsigned long long K = keptm[ch];
        #pragma unroll
        for (int q2 = 0; q2 < 2; ++q2) {
          if (256*q2 >= V) break;
          if (((am >> q2) & 1u) && (wid + 4*q2) > ch) {
            if (ckill[q2][ch][t] & K) am &= ~(1u << q2);
          }
        }
      }
    }

    // write ONLY kept rows (prep3 already zeroed the output)
    #pragma unroll
    for (int q = 0; q < 2; ++q) {
      int j = t + 256*q;
      if (j < V && ((km >> q) & 1u)) {
        int row = cls*R_N + j;
        float4 b = fbox4[cls*MAXFV + j];
        out[row*5+0]=b.x; out[row*5+1]=b.y; out[row*5+2]=b.z; out[row*5+3]=b.w;
        out[row*5+4]=sprobg[cls*MAXFV + j];
        out[OUT_LBL  + row] = (float)(cls + 1);
        out[OUT_KEEP + row] = 1.f;
      }
    }
    return;
  }

  // ---- V > MAXFV: release builders (they will skip), run proven in-block NMS ----
  if (t == 0) {
    vcls[cls] = V;
    __threadfence();
    __hip_atomic_store(&ready[cls], 1, __ATOMIC_RELEASE, __HIP_MEMORY_SCOPE_AGENT);
  }
  #pragma unroll
  for (int u = 0; u < 8; ++u) {
    int r = t + 256 * u;
    if (r < R_N) {
      double4 bd = dbox_all[cls * R_N + r];
      sbd[r][0]=bd.x; sbd[r][1]=bd.y; sbd[r][2]=bd.z; sbd[r][3]=bd.w;
    }
  }
  __syncthreads();

  int   idx8[8];
  float fx0[8], fx1[8], fx2[8], fx3[8], far5[8], pr[8];
  unsigned am = 0, km = 0;
  #pragma unroll
  for (int q = 0; q < 8; ++q) {
    int j = t + 256 * q;
    fx0[q]=fx1[q]=fx2[q]=fx3[q]=far5[q]=pr[q]=0.f; idx8[q]=0;
    if (j < V) {
      int idx = (int)(~(unsigned)keys[j].y);
      idx8[q] = idx;
      double a0=sbd[idx][0], a1=sbd[idx][1], a2=sbd[idx][2], a3=sbd[idx][3];
      fx0[q]=(float)a0; fx1[q]=(float)a1; fx2[q]=(float)a2; fx3[q]=(float)a3;
      far5[q]=(float)((a2-a0)*(a3-a1));
      pr[q]=(float)__longlong_as_double((long long)keys[j].x);
      am |= 1u << q;
    }
  }

  #pragma unroll
  for (int q = 0; q < 8; ++q) {
    if (256 * q >= V) break;
    for (int sub = 0; sub < 4; ++sub) {
      const int ch = 4 * q + sub;
      if (64 * ch >= V) break;
      const int buf = ch & 1;
      if (wid == sub) {
        bool a = ((am >> q) & 1u) != 0u;
        int myidx = idx8[q];
        float f0=fx0[q], f1=fx1[q], f2=fx2[q], f3=fx3[q], fa=far5[q];
        unsigned long long m = __ballot(a);
        unsigned long long kept = 0;
        while (m) {
          int i = __ffsll(m) - 1;
          m &= m - 1;
          kept |= 1ull << i;
          float k0=__shfl(f0,i), k1=__shfl(f1,i), k2=__shfl(f2,i), k3=__shfl(f3,i), ka=__shfl(fa,i);
          bool aliveL = ((m >> lane) & 1ull) != 0ull;
          float ty=fmaxf(k0,f0), tx=fmaxf(k1,f1);
          float by=fminf(k2,f2), bz=fminf(k3,f3);
          float w0=fmaxf(by-ty,0.f), w1=fmaxf(bz-tx,0.f);
          float inter=w0*w1;
          float uni=fmaxf(ka+fa-inter, 1e-9f);
          float rhs=0.3f*uni;
          bool kill = aliveL && (inter > rhs + FMARGIN);
          bool amb  = aliveL && !kill && (inter > rhs - FMARGIN);
          if (__any(amb)) {
            int kidx = __shfl(myidx, i);
            double b0=sbd[kidx][0], b1=sbd[kidx][1], b2=sbd[kidx][2], b3=sbd[kidx][3];
            double bar=(b2-b0)*(b3-b1);
            if (amb) {
              double a0=sbd[myidx][0], a1=sbd[myidx][1], a2=sbd[myidx][2], a3=sbd[myidx][3];
              double aar=(a2-a0)*(a3-a1);
              double ty_=fmax(b0,a0), tx_=fmax(b1,a1);
              double by_=fmin(b2,a2), bz_=fmin(b3,a3);
              double w0_=fmax(by_-ty_,0.0), w1_=fmax(bz_-tx_,0.0);
              double in_=w0_*w1_;
              double un_=bar+aar-in_;
              if (in_/fmax(un_,1e-9) > 0.3) kill = true;
            }
          }
          m &= ~__ballot(kill);
        }
        am &= ~(1u << q);
        if ((kept >> lane) & 1ull) {
          km |= 1u << q;
          int kpos = (int)__popcll(kept & ((1ull << lane) - 1ull));
          double a0=sbd[myidx][0], a1=sbd[myidx][1], a2=sbd[myidx][2], a3=sbd[myidx][3];
          klist64[buf][kpos][0]=a0; klist64[buf][kpos][1]=a1;
          klist64[buf][kpos][2]=a2; klist64[buf][kpos][3]=a3;
          klist64[buf][kpos][4]=(a2-a0)*(a3-a1);
          klist32[buf][kpos][0]=f0; klist32[buf][kpos][1]=f1;
          klist32[buf][kpos][2]=f2; klist32[buf][kpos][3]=f3; klist32[buf][kpos][4]=fa;
        }
        if (lane == 0) kcnt[buf] = (int)__popcll(kept);
      }
      __syncthreads();
      const int nk = kcnt[buf];
      const int jmin = 64 * (ch + 1);
      for (int n = 0; n < nk; ++n) {
        float k0=klist32[buf][n][0], k1=klist32[buf][n][1];
        float k2=klist32[buf][n][2], k3=klist32[buf][n][3], ka=klist32[buf][n][4];
        #pragma unroll
        for (int q2 = 0; q2 < 8; ++q2) {
          if (256 * q2 >= V) break;
          int j2 = t + 256 * q2;
          if (((am >> q2) & 1u) && j2 >= jmin) {
            float ty=fmaxf(k0,fx0[q2]), tx=fmaxf(k1,fx1[q2]);
            float by=fminf(k2,fx2[q2]), bz=fminf(k3,fx3[q2]);
            float w0=fmaxf(by-ty,0.f), w1=fmaxf(bz-tx,0.f);
            float inter=w0*w1;
            float uni=fmaxf(ka+far5[q2]-inter, 1e-9f);
            float rhs=0.3f*uni;
            if (inter > rhs + FMARGIN) {
              am &= ~(1u << q2);
            } else if (inter > rhs - FMARGIN) {
              int idx = idx8[q2];
              double a0=sbd[idx][0], a1=sbd[idx][1], a2=sbd[idx][2], a3=sbd[idx][3];
              double ar_=(a2-a0)*(a3-a1);
              double b0=klist64[buf][n][0], b1=klist64[buf][n][1];
              double b2=klist64[buf][n][2], b3=klist64[buf][n][3], br=klist64[buf][n][4];
              double ty_=fmax(b0,a0), tx_=fmax(b1,a1);
              double by_=fmin(b2,a2), bz_=fmin(b3,a3);
              double w0_=fmax(by_-ty_,0.0), w1_=fmax(bz_-tx_,0.0);
              double in_=w0_*w1_;
              double un_=br+ar_-in_;
              if (in_/fmax(un_,1e-9) > 0.3) am &= ~(1u << q2);
            }
          }
        }
      }
    }
  }

  #pragma unroll
  for (int u = 0; u < 8; ++u) {
    int j = t + 256 * u;
    if (j < R_N) {
      int row = cls * R_N + j;
      bool k = ((km >> u) & 1u) != 0u;
      out[row*5+0] = k ? fx0[u] : 0.f;
      out[row*5+1] = k ? fx1[u] : 0.f;
      out[row*5+2] = k ? fx2[u] : 0.f;
      out[row*5+3] = k ? fx3[u] : 0.f;
      out[row*5+4] = k ? pr[u]  : 0.f;
      out[OUT_LBL  + row] = k ? (float)(cls + 1) : 0.f;
      out[OUT_KEEP + row] = k ? 1.f : 0.f;
    }
  }
}

// ---- standalone fallback (no-ws): R13's proven self-contained kernel ----
__global__ __launch_bounds__(256) void sortexport_kernel(
    const float* __restrict__ rois, const float* __restrict__ loc,
    const float* __restrict__ score,
    const void* __restrict__ hptr, const void* __restrict__ wptr,
    float* __restrict__ out)
{
  __shared__ double sbd[R_N][4];
  __shared__ ulonglong2 keys[2048];
  __shared__ double klist64[2][64][5];
  __shared__ float  klist32[2][64][5];
  __shared__ int kcnt[2];
  __shared__ int wsum[4];

  const int cls = blockIdx.x;
  const int t = threadIdx.x;
  const int lane = t & 63, wid = t >> 6;
  const double H = read_dim(hptr), W = read_dim(wptr);

  ulonglong2 rk[8];
  int vmask = 0;
  #pragma unroll
  for (int u = 0; u < 8; ++u) {
    int r = t + 256 * u;
    rk[u] = make_ulonglong2(0ull, 0ull);
    if (r < R_N) {
      const float* sc = score + r * C1;
      double m = (double)sc[0];
      #pragma unroll
      for (int k = 1; k < C1; ++k) m = fmax(m, (double)sc[k]);
      double s = 0.0;
      #pragma unroll
      for (int k = 0; k < C1; ++k) s += exp((double)sc[k] - m);
      double p = exp((double)sc[cls + 1] - m) / s;
      const float* l4 = loc + r * 84 + (cls + 1) * 4;
      double dy = (double)l4[0], dx = (double)l4[1];
      double eh = exp((double)l4[2]), ew = exp((double)l4[3]);
      double b0 = (double)rois[r*4+0], b1 = (double)rois[r*4+1];
      double b2 = (double)rois[r*4+2], b3 = (double)rois[r*4+3];
      double sh  = b2 - b0,       sw  = b3 - b1;
      double scy = b0 + 0.5*sh,   scx = b1 + 0.5*sw;
      double cy = dy*sh + scy,    cx = dx*sw + scx;
      double hh = eh*sh,          ww = ew*sw;
      sbd[r][0] = fmin(fmax(cy - 0.5*hh, 0.0), H);
      sbd[r][1] = fmin(fmax(cx - 0.5*ww, 0.0), W);
      sbd[r][2] = fmin(fmax(cy + 0.5*hh, 0.0), H);
      sbd[r][3] = fmin(fmax(cx + 0.5*ww, 0.0), W);
      if (p > 0.05) {
        rk[u] = make_ulonglong2((unsigned long long)__double_as_longlong(p),
                                (unsigned long long)(unsigned int)(~r));
        vmask |= 1 << u;
      }
    }
  }

  int cnt = __popc(vmask);
  int x = cnt;
  #pragma unroll
  for (int off = 1; off < 64; off <<= 1) {
    int y = __shfl_up(x, off);
    if (lane >= off) x += y;
  }
  if (lane == 63) wsum[wid] = x;
  __syncthreads();
  int woff = 0;
  #pragma unroll
  for (int w2 = 0; w2 < 4; ++w2) { int s = wsum[w2]; if (w2 < wid) woff += s; }
  const int V = wsum[0] + wsum[1] + wsum[2] + wsum[3];
  int pos = woff + x - cnt;
  #pragma unroll
  for (int u = 0; u < 8; ++u)
    if ((vmask >> u) & 1) keys[pos++] = rk[u];

  int NSORT = 64; while (NSORT < V) NSORT <<= 1;
  for (int j = V + t; j < NSORT; j += 256)
    keys[j] = make_ulonglong2(0ull, (unsigned long long)(unsigned int)(~(unsigned)j));
  __syncthreads();

  for (int k = 2; k <= NSORT; k <<= 1) {
    for (int js = k >> 1; js > 0; js >>= 1) {
      for (int p = t; p < (NSORT >> 1); p += 256) {
        int i = ((p & ~(js - 1)) << 1) | (p & (js - 1));
        int j = i | js;
        ulonglong2 a = keys[i], b = keys[j];
        bool altb = (a.x < b.x) || (a.x == b.x && a.y < b.y);
        if (altb == ((i & k) == 0)) { keys[i] = b; keys[j] = a; }
      }
      __syncthreads();
    }
  }

  int   idx8[8];
  float fx0[8], fx1[8], fx2[8], fx3[8], far5[8], pr[8];
  unsigned am = 0, km = 0;
  #pragma unroll
  for (int q = 0; q < 8; ++q) {
    int j = t + 256 * q;
    fx0[q]=fx1[q]=fx2[q]=fx3[q]=far5[q]=pr[q]=0.f; idx8[q]=0;
    if (j < V) {
      int idx = (int)(~(unsigned)keys[j].y);
      idx8[q] = idx;
      double a0=sbd[idx][0], a1=sbd[idx][1], a2=sbd[idx][2], a3=sbd[idx][3];
      fx0[q]=(float)a0; fx1[q]=(float)a1; fx2[q]=(float)a2; fx3[q]=(float)a3;
      far5[q]=(float)((a2-a0)*(a3-a1));
      pr[q]=(float)__longlong_as_double((long long)keys[j].x);
      am |= 1u << q;
    }
  }

  #pragma unroll
  for (int q = 0; q < 8; ++q) {
    if (256 * q >= V) break;
    for (int sub = 0; sub < 4; ++sub) {
      const int ch = 4 * q + sub;
      if (64 * ch >= V) break;
      const int buf = ch & 1;
      if (wid == sub) {
        bool a = ((am >> q) & 1u) != 0u;
        int myidx = idx8[q];
        float f0=fx0[q], f1=fx1[q], f2=fx2[q], f3=fx3[q], fa=far5[q];
        unsigned long long m = __ballot(a);
        unsigned long long kept = 0;
        while (m) {
          int i = __ffsll(m) - 1;
          m &= m - 1;
          kept |= 1ull << i;
          float k0=__shfl(f0,i), k1=__shfl(f1,i), k2=__shfl(f2,i), k3=__shfl(f3,i), ka=__shfl(fa,i);
          bool aliveL = ((m >> lane) & 1ull) != 0ull;
          float ty=fmaxf(k0,f0), tx=fmaxf(k1,f1);
          float by=fminf(k2,f2), bz=fminf(k3,f3);
          float w0=fmaxf(by-ty,0.f), w1=fmaxf(bz-tx,0.f);
          float inter=w0*w1;
          float uni=fmaxf(ka+fa-inter, 1e-9f);
          float rhs=0.3f*uni;
          bool kill = aliveL && (inter > rhs + FMARGIN);
          bool amb  = aliveL && !kill && (inter > rhs - FMARGIN);
          if (__any(amb)) {
            int kidx = __shfl(myidx, i);
            double b0=sbd[kidx][0], b1=sbd[kidx][1], b2=sbd[kidx][2], b3=sbd[kidx][3];
            double bar=(b2-b0)*(b3-b1);
            if (amb) {
              double a0=sbd[myidx][0], a1=sbd[myidx][1], a2=sbd[myidx][2], a3=sbd[myidx][3];
              double aar=(a2-a0)*(a3-a1);
              double ty_=fmax(b0,a0), tx_=fmax(b1,a1);
              double by_=fmin(b2,a2), bz_=fmin(b3,a3);
              double w0_=fmax(by_-ty_,0.0), w1_=fmax(bz_-tx_,0.0);
              double in_=w0_*w1_;
              double un_=bar+aar-in_;
              if (in_/fmax(un_,1e-9) > 0.3) kill = true;
            }
          }
          m &= ~__ballot(kill);
        }
        am &= ~(1u << q);
        if ((kept >> lane) & 1ull) {
          km |= 1u << q;
          int kpos = (int)__popcll(kept & ((1ull << lane) - 1ull));
          double a0=sbd[myidx][0], a1=sbd[myidx][1], a2=sbd[myidx][2], a3=sbd[myidx][3];
          klist64[buf][kpos][0]=a0; klist64[buf][kpos][1]=a1;
          klist64[buf][kpos][2]=a2; klist64[buf][kpos][3]=a3;
          klist64[buf][kpos][4]=(a2-a0)*(a3-a1);
          klist32[buf][kpos][0]=f0; klist32[buf][kpos][1]=f1;
          klist32[buf][kpos][2]=f2; klist32[buf][kpos][3]=f3; klist32[buf][kpos][4]=fa;
        }
        if (lane == 0) kcnt[buf] = (int)__popcll(kept);
      }
      __syncthreads();
      const int nk = kcnt[buf];
      const int jmin = 64 * (ch + 1);
      for (int n = 0; n < nk; ++n) {
        float k0=klist32[buf][n][0], k1=klist32[buf][n][1];
        float k2=klist32[buf][n][2], k3=klist32[buf][n][3], ka=klist32[buf][n][4];
        #pragma unroll
        for (int q2 = 0; q2 < 8; ++q2) {
          if (256 * q2 >= V) break;
          int j2 = t + 256 * q2;
          if (((am >> q2) & 1u) && j2 >= jmin) {
            float ty=fmaxf(k0,fx0[q2]), tx=fmaxf(k1,fx1[q2]);
            float by=fminf(k2,fx2[q2]), bz=fminf(k3,fx3[q2]);
            float w0=fmaxf(by-ty,0.f), w1=fmaxf(bz-tx,0.f);
            float inter=w0*w1;
            float uni=fmaxf(ka+far5[q2]-inter, 1e-9f);
            float rhs=0.3f*uni;
            if (inter > rhs + FMARGIN) {
              am &= ~(1u << q2);
            } else if (inter > rhs - FMARGIN) {
              int idx = idx8[q2];
              double a0=sbd[idx][0], a1=sbd[idx][1], a2=sbd[idx][2], a3=sbd[idx][3];
              double ar_=(a2-a0)*(a3-a1);
              double b0=klist64[buf][n][0], b1=klist64[buf][n][1];
              double b2=klist64[buf][n][2], b3=klist64[buf][n][3], br=klist64[buf][n][4];
              double ty_=fmax(b0,a0), tx_=fmax(b1,a1);
              double by_=fmin(b2,a2), bz_=fmin(b3,a3);
              double w0_=fmax(by_-ty_,0.0), w1_=fmax(bz_-tx_,0.0);
              double in_=w0_*w1_;
              double un_=br+ar_-in_;
              if (in_/fmax(un_,1e-9) > 0.3) am &= ~(1u << q2);
            }
          }
        }
      }
    }
  }

  #pragma unroll
  for (int u = 0; u < 8; ++u) {
    int j = t + 256 * u;
    if (j < R_N) {
      int row = cls * R_N + j;
      bool k = ((km >> u) & 1u) != 0u;
      out[row*5+0] = k ? fx0[u] : 0.f;
      out[row*5+1] = k ? fx1[u] : 0.f;
      out[row*5+2] = k ? fx2[u] : 0.f;
      out[row*5+3] = k ? fx3[u] : 0.f;
      out[row*5+4] = k ? pr[u]  : 0.f;
      out[OUT_LBL  + row] = k ? (float)(cls + 1) : 0.f;
      out[OUT_KEEP + row] = k ? 1.f : 0.f;
    }
  }
}

extern "C" void kernel_launch(void* const* d_in, const int* in_sizes, int n_in,
                              void* d_out, int out_size, void* d_ws, size_t ws_size,
                              hipStream_t stream) {
  const float* rois  = (const float*)d_in[0];
  const float* loc   = (const float*)d_in[1];
  const float* score = (const float*)d_in[2];
  const void*  hp    = d_in[3];
  const void*  wp    = d_in[4];
  float* out = (float*)d_out;

  // ws layout (bytes):
  //   dbox_all f64x4[20*2000] @ 0          1,280,000
  //   prob_t   f64[20*2000]   @ 1,280,000    320,000
  //   fbox4    f32x4[20*512]  @ 1,600,000    163,840
  //   dbox4s   f64x4[20*512]  @ 1,763,840    327,680
  //   farea    f32[20*512]    @ 2,091,520     40,960
  //   sprob    f32[20*512]    @ 2,132,480     40,960
  //   kw       u64[20*512*8]  @ 2,173,440    655,360
  //   vcls     i32[20]        @ 2,828,800         80
  //   flags    i32[40]        @ 2,828,880        160   (ready[20] | done[20])
  char* wsb = (char*)d_ws;
  double4* dbox_all = (double4*)(wsb + 0);
  double*  prob_t   = (double*)(wsb + 1280000);
  float4*  fbox4    = (float4*)(wsb + 1600000);
  double4* dbox4s   = (double4*)(wsb + 1763840);
  float*   farea    = (float*)(wsb + 2091520);
  float*   sprob    = (float*)(wsb + 2132480);
  unsigned long long* kw = (unsigned long long*)(wsb + 2173440);
  int*     vcls     = (int*)(wsb + 2828800);
  int*     flags    = (int*)(wsb + 2828880);
  int*     ready    = flags;
  int*     done     = flags + 20;
  const size_t WS_NEED = 2829040;

  if (ws_size >= WS_NEED) {
    prep3_kernel<<<dim3(168), dim3(256), 0, stream>>>(rois, loc, score, hp, wp,
                                                      dbox_all, prob_t, out, flags);
    nmspipe_kernel<<<dim3(NCLS, 10), dim3(256), 0, stream>>>(
        out, dbox_all, prob_t, fbox4, dbox4s, farea, sprob, vcls, kw, ready, done);
  } else {
    sortexport_kernel<<<dim3(NCLS), dim3(256), 0, stream>>>(
        rois, loc, score, hp, wp, out);
  }
}

// Round 15
// 52.468 us; speedup vs baseline: 1.5579x; 1.5579x over previous
//
#include <hip/hip_runtime.h>
#include <cstdint>

#pragma clang fp contract(off)

#define R_N   2000
#define C1    21
#define NCLS  20
#define MAXFV 512
#define OUT_LBL   200000
#define OUT_KEEP  240000
#define FMARGIN   4.0f      // |inter-0.3uni| f32 err bound ~0.5 px^2; 4.0 = big safety

// wave-level LDS drain: orders this wave's ds ops; windows are wave-private
#define WAVE_SYNC() do {                                        \
  __builtin_amdgcn_sched_barrier(0);                            \
  asm volatile("s_waitcnt lgkmcnt(0)" ::: "memory");            \
  __builtin_amdgcn_sched_barrier(0);                            \
} while (0)

__device__ __forceinline__ double read_dim(const void* p) {
  int iv = *(const int*)p;
  if (iv >= 1 && iv <= 1000000) return (double)iv;
  float fv = *(const float*)p;
  if (fv >= 1.0f && fv <= 1000000.0f) return (double)fv;
  return *(const double*)p;
}

// ---- K1: wide decode + softmax + output zeroing ----
__global__ __launch_bounds__(256) void prep3_kernel(
    const float* __restrict__ rois, const float* __restrict__ loc,
    const float* __restrict__ score,
    const void* __restrict__ hptr, const void* __restrict__ wptr,
    double4* __restrict__ dbox_all, double* __restrict__ prob_t,
    float* __restrict__ out)
{
  int tid = blockIdx.x * 256 + threadIdx.x;
  // zero the whole output (280000 f32 = 70000 float4); scan writes only kept rows
  float4 z4 = make_float4(0.f, 0.f, 0.f, 0.f);
  for (int z = tid; z < 70000; z += 168 * 256) ((float4*)out)[z] = z4;

  if (tid < 40000) {
    int r = tid % R_N, c = tid / R_N;
    const double H = read_dim(hptr), W = read_dim(wptr);
    const float* l4 = loc + r * 84 + (c + 1) * 4;
    double dy = (double)l4[0], dx = (double)l4[1];
    double eh = exp((double)l4[2]), ew = exp((double)l4[3]);
    double b0 = (double)rois[r*4+0], b1 = (double)rois[r*4+1];
    double b2 = (double)rois[r*4+2], b3 = (double)rois[r*4+3];
    double sh  = b2 - b0,       sw  = b3 - b1;
    double scy = b0 + 0.5*sh,   scx = b1 + 0.5*sw;
    double cy = dy*sh + scy,    cx = dx*sw + scx;
    double hh = eh*sh,          ww = ew*sw;
    double y1 = fmin(fmax(cy - 0.5*hh, 0.0), H);
    double x1 = fmin(fmax(cx - 0.5*ww, 0.0), W);
    double y2 = fmin(fmax(cy + 0.5*hh, 0.0), H);
    double x2 = fmin(fmax(cx + 0.5*ww, 0.0), W);
    dbox_all[c * R_N + r] = make_double4(y1, x1, y2, x2);
  } else if (tid >= 40960 && tid < 40960 + R_N) {
    int r = tid - 40960;
    const float* sc = score + r * C1;
    double m = (double)sc[0];
    #pragma unroll
    for (int k = 1; k < C1; ++k) m = fmax(m, (double)sc[k]);
    double e[C1]; double s = 0.0;
    #pragma unroll
    for (int k = 0; k < C1; ++k) { e[k] = exp((double)sc[k] - m); s += e[k]; }
    #pragma unroll
    for (int c = 0; c < NCLS; ++c) prob_t[c * R_N + r] = e[c + 1] / s;
  }
}

// ---- K2: per-class compact + bitonic sort -> sorted slot arrays (fast) or full NMS (fallback)
__global__ __launch_bounds__(256) void sortexport_kernel(
    const float* __restrict__ rois, const float* __restrict__ loc,
    const float* __restrict__ score,
    const void* __restrict__ hptr, const void* __restrict__ wptr,
    float* __restrict__ out,
    const double4* __restrict__ dbox_all, const double* __restrict__ prob_t,
    float4* __restrict__ fbox4, double4* __restrict__ dbox4s,
    float* __restrict__ farea, float* __restrict__ sprobg,
    int* __restrict__ vcls, int mode)   // mode 1 = ws fast path; 0 = self-contained fallback
{
  __shared__ double sbd[R_N][4];          // fallback only
  __shared__ ulonglong2 keys[2048];
  __shared__ double klist64[2][64][5];
  __shared__ float  klist32[2][64][5];
  __shared__ int kcnt[2];
  __shared__ int wsum[4];

  const int cls = blockIdx.x;
  const int t = threadIdx.x;
  const int lane = t & 63, wid = t >> 6;

  // phase 1: probs -> keys
  ulonglong2 rk[8];
  int vmask = 0;
  #pragma unroll
  for (int u = 0; u < 8; ++u) {
    int r = t + 256 * u;
    rk[u] = make_ulonglong2(0ull, 0ull);
    if (r < R_N) {
      double p;
      if (mode) {
        p = prob_t[cls * R_N + r];
      } else {
        const float* sc = score + r * C1;
        double m = (double)sc[0];
        #pragma unroll
        for (int k = 1; k < C1; ++k) m = fmax(m, (double)sc[k]);
        double s = 0.0;
        #pragma unroll
        for (int k = 0; k < C1; ++k) s += exp((double)sc[k] - m);
        p = exp((double)sc[cls + 1] - m) / s;
      }
      if (p > 0.05) {
        rk[u] = make_ulonglong2((unsigned long long)__double_as_longlong(p),
                                (unsigned long long)(unsigned int)(~r));
        vmask |= 1 << u;
      }
    }
  }

  // phase 2: ballot-scan compaction
  int cnt = __popc(vmask);
  int x = cnt;
  #pragma unroll
  for (int off = 1; off < 64; off <<= 1) {
    int y = __shfl_up(x, off);
    if (lane >= off) x += y;
  }
  if (lane == 63) wsum[wid] = x;
  __syncthreads();
  int woff = 0;
  #pragma unroll
  for (int w2 = 0; w2 < 4; ++w2) { int s = wsum[w2]; if (w2 < wid) woff += s; }
  const int V = wsum[0] + wsum[1] + wsum[2] + wsum[3];
  int pos = woff + x - cnt;
  #pragma unroll
  for (int u = 0; u < 8; ++u)
    if ((vmask >> u) & 1) keys[pos++] = rk[u];

  int NSORT = 64; while (NSORT < V) NSORT <<= 1;
  for (int j = V + t; j < NSORT; j += 256)
    keys[j] = make_ulonglong2(0ull, (unsigned long long)(unsigned int)(~(unsigned)j));
  __syncthreads();

  // phase 3: bitonic sort, descending (prob desc, idx asc) — same network as proven,
  // js<=64 steps are wave-local (128-slot aligned windows), js>=128 block-wide.
  const int wb = 128 * wid;                       // this wave's window base
  int wsz = NSORT - wb; if (wsz > 128) wsz = 128; // window size (<=0 -> idle wave)
  for (int k = 2; k <= NSORT; k <<= 1) {
    int js = k >> 1;
    if (js >= 128) {
      for (; js >= 128; js >>= 1) {
        __syncthreads();
        for (int p = t; p < (NSORT >> 1); p += 256) {
          int i = ((p & ~(js - 1)) << 1) | (p & (js - 1));
          int j = i | js;
          ulonglong2 a = keys[i], b = keys[j];
          bool altb = (a.x < b.x) || (a.x == b.x && a.y < b.y);
          if (altb == ((i & k) == 0)) { keys[i] = b; keys[j] = a; }
        }
      }
      __syncthreads();
    }
    if (wsz > 0) {
      for (; js > 0; js >>= 1) {
        if (lane < (wsz >> 1)) {
          int i = wb + (((lane & ~(js - 1)) << 1) | (lane & (js - 1)));
          int j = i | js;
          ulonglong2 a = keys[i], b = keys[j];
          bool altb = (a.x < b.x) || (a.x == b.x && a.y < b.y);
          if (altb == ((i & k) == 0)) { keys[i] = b; keys[j] = a; }
        }
        WAVE_SYNC();
      }
    }
  }
  __syncthreads();

  if (mode && V <= MAXFV) {
    // fast path: export sorted slot arrays via dbox_all gather (proven)
    for (int j = t; j < V; j += 256) {
      ulonglong2 kj = keys[j];
      int idx = (int)(~(unsigned)kj.y);
      double4 bd = dbox_all[cls * R_N + idx];
      int g = cls * MAXFV + j;
      fbox4[g]  = make_float4((float)bd.x, (float)bd.y, (float)bd.z, (float)bd.w);
      dbox4s[g] = bd;
      farea[g]  = (float)((bd.z - bd.x) * (bd.w - bd.y));
      sprobg[g] = (float)__longlong_as_double((long long)kj.x);
    }
    if (t == 0) vcls[cls] = V;
    return;
  }
  if (mode && t == 0) vcls[cls] = V;   // V > MAXFV: build/scan will skip this class

  // ---- fallback: fill sbd, proven shuffle-NMS, write all rows ----
  #pragma unroll
  for (int u = 0; u < 8; ++u) {
    int r = t + 256 * u;
    if (r < R_N) {
      if (mode) {
        double4 bd = dbox_all[cls * R_N + r];
        sbd[r][0]=bd.x; sbd[r][1]=bd.y; sbd[r][2]=bd.z; sbd[r][3]=bd.w;
      } else {
        const double H = read_dim(hptr), W = read_dim(wptr);
        const float* l4 = loc + r * 84 + (cls + 1) * 4;
        double dy = (double)l4[0], dx = (double)l4[1];
        double eh = exp((double)l4[2]), ew = exp((double)l4[3]);
        double b0 = (double)rois[r*4+0], b1 = (double)rois[r*4+1];
        double b2 = (double)rois[r*4+2], b3 = (double)rois[r*4+3];
        double sh  = b2 - b0,       sw  = b3 - b1;
        double scy = b0 + 0.5*sh,   scx = b1 + 0.5*sw;
        double cy = dy*sh + scy,    cx = dx*sw + scx;
        double hh = eh*sh,          ww = ew*sw;
        sbd[r][0] = fmin(fmax(cy - 0.5*hh, 0.0), H);
        sbd[r][1] = fmin(fmax(cx - 0.5*ww, 0.0), W);
        sbd[r][2] = fmin(fmax(cy + 0.5*hh, 0.0), H);
        sbd[r][3] = fmin(fmax(cx + 0.5*ww, 0.0), W);
      }
    }
  }
  __syncthreads();

  int   idx8[8];
  float fx0[8], fx1[8], fx2[8], fx3[8], far5[8], pr[8];
  unsigned am = 0, km = 0;
  #pragma unroll
  for (int q = 0; q < 8; ++q) {
    int j = t + 256 * q;
    fx0[q]=fx1[q]=fx2[q]=fx3[q]=far5[q]=pr[q]=0.f; idx8[q]=0;
    if (j < V) {
      int idx = (int)(~(unsigned)keys[j].y);
      idx8[q] = idx;
      double a0=sbd[idx][0], a1=sbd[idx][1], a2=sbd[idx][2], a3=sbd[idx][3];
      fx0[q]=(float)a0; fx1[q]=(float)a1; fx2[q]=(float)a2; fx3[q]=(float)a3;
      far5[q]=(float)((a2-a0)*(a3-a1));
      pr[q]=(float)__longlong_as_double((long long)keys[j].x);
      am |= 1u << q;
    }
  }

  #pragma unroll
  for (int q = 0; q < 8; ++q) {
    if (256 * q >= V) break;
    for (int sub = 0; sub < 4; ++sub) {
      const int ch = 4 * q + sub;
      if (64 * ch >= V) break;
      const int buf = ch & 1;
      if (wid == sub) {
        const int s = 64 * ch + lane;
        bool a = ((am >> q) & 1u) != 0u;
        int myidx = idx8[q];
        float f0=fx0[q], f1=fx1[q], f2=fx2[q], f3=fx3[q], fa=far5[q];
        unsigned long long m = __ballot(a);
        unsigned long long kept = 0;
        while (m) {
          int i = __ffsll(m) - 1;
          m &= m - 1;
          kept |= 1ull << i;
          float k0=__shfl(f0,i), k1=__shfl(f1,i), k2=__shfl(f2,i), k3=__shfl(f3,i), ka=__shfl(fa,i);
          bool aliveL = ((m >> lane) & 1ull) != 0ull;
          float ty=fmaxf(k0,f0), tx=fmaxf(k1,f1);
          float by=fminf(k2,f2), bz=fminf(k3,f3);
          float w0=fmaxf(by-ty,0.f), w1=fmaxf(bz-tx,0.f);
          float inter=w0*w1;
          float uni=fmaxf(ka+fa-inter, 1e-9f);
          float rhs=0.3f*uni;
          bool kill = aliveL && (inter > rhs + FMARGIN);
          bool amb  = aliveL && !kill && (inter > rhs - FMARGIN);
          if (__any(amb)) {
            int kidx = __shfl(myidx, i);
            double b0=sbd[kidx][0], b1=sbd[kidx][1], b2=sbd[kidx][2], b3=sbd[kidx][3];
            double bar=(b2-b0)*(b3-b1);
            if (amb) {
              double a0=sbd[myidx][0], a1=sbd[myidx][1], a2=sbd[myidx][2], a3=sbd[myidx][3];
              double aar=(a2-a0)*(a3-a1);
              double ty_=fmax(b0,a0), tx_=fmax(b1,a1);
              double by_=fmin(b2,a2), bz_=fmin(b3,a3);
              double w0_=fmax(by_-ty_,0.0), w1_=fmax(bz_-tx_,0.0);
              double in_=w0_*w1_;
              double un_=bar+aar-in_;
              if (in_/fmax(un_,1e-9) > 0.3) kill = true;
            }
          }
          m &= ~__ballot(kill);
        }
        am &= ~(1u << q);
        if ((kept >> lane) & 1ull) {
          km |= 1u << q;
          int kpos = (int)__popcll(kept & ((1ull << lane) - 1ull));
          double a0=sbd[myidx][0], a1=sbd[myidx][1], a2=sbd[myidx][2], a3=sbd[myidx][3];
          klist64[buf][kpos][0]=a0; klist64[buf][kpos][1]=a1;
          klist64[buf][kpos][2]=a2; klist64[buf][kpos][3]=a3;
          klist64[buf][kpos][4]=(a2-a0)*(a3-a1);
          klist32[buf][kpos][0]=f0; klist32[buf][kpos][1]=f1;
          klist32[buf][kpos][2]=f2; klist32[buf][kpos][3]=f3; klist32[buf][kpos][4]=fa;
        }
        if (lane == 0) kcnt[buf] = (int)__popcll(kept);
      }
      __syncthreads();
      const int nk = kcnt[buf];
      const int jmin = 64 * (ch + 1);
      for (int n = 0; n < nk; ++n) {
        float k0=klist32[buf][n][0], k1=klist32[buf][n][1];
        float k2=klist32[buf][n][2], k3=klist32[buf][n][3], ka=klist32[buf][n][4];
        #pragma unroll
        for (int q2 = 0; q2 < 8; ++q2) {
          if (256 * q2 >= V) break;
          int j2 = t + 256 * q2;
          if (((am >> q2) & 1u) && j2 >= jmin) {
            float ty=fmaxf(k0,fx0[q2]), tx=fmaxf(k1,fx1[q2]);
            float by=fminf(k2,fx2[q2]), bz=fminf(k3,fx3[q2]);
            float w0=fmaxf(by-ty,0.f), w1=fmaxf(bz-tx,0.f);
            float inter=w0*w1;
            float uni=fmaxf(ka+far5[q2]-inter, 1e-9f);
            float rhs=0.3f*uni;
            if (inter > rhs + FMARGIN) {
              am &= ~(1u << q2);
            } else if (inter > rhs - FMARGIN) {
              int idx = idx8[q2];
              double a0=sbd[idx][0], a1=sbd[idx][1], a2=sbd[idx][2], a3=sbd[idx][3];
              double ar_=(a2-a0)*(a3-a1);
              double b0=klist64[buf][n][0], b1=klist64[buf][n][1];
              double b2=klist64[buf][n][2], b3=klist64[buf][n][3], br=klist64[buf][n][4];
              double ty_=fmax(b0,a0), tx_=fmax(b1,a1);
              double by_=fmin(b2,a2), bz_=fmin(b3,a3);
              double w0_=fmax(by_-ty_,0.0), w1_=fmax(bz_-tx_,0.0);
              double in_=w0_*w1_;
              double un_=br+ar_-in_;
              if (in_/fmax(un_,1e-9) > 0.3) am &= ~(1u << q2);
            }
          }
        }
      }
    }
  }

  #pragma unroll
  for (int u = 0; u < 8; ++u) {
    int j = t + 256 * u;
    if (j < R_N) {
      int row = cls * R_N + j;
      bool k = ((km >> u) & 1u) != 0u;
      out[row*5+0] = k ? fx0[u] : 0.f;
      out[row*5+1] = k ? fx1[u] : 0.f;
      out[row*5+2] = k ? fx2[u] : 0.f;
      out[row*5+3] = k ? fx3[u] : 0.f;
      out[row*5+4] = k ? pr[u]  : 0.f;
      out[OUT_LBL  + row] = k ? (float)(cls + 1) : 0.f;
      out[OUT_KEEP + row] = k ? 1.f : 0.f;
    }
  }
}

// ---- K3: parallel kill-word build (180 blocks). thread = one (j, w): 64 pair tests ----
__global__ __launch_bounds__(256) void build_kernel(
    const float4* __restrict__ fbox4, const float* __restrict__ farea,
    const double4* __restrict__ dbox4s, const int* __restrict__ vcls,
    unsigned long long* __restrict__ kw)
{
  const int cls = blockIdx.x;
  const int V = vcls[cls];
  if (V > MAXFV) return;
  int n = blockIdx.y * 256 + threadIdx.x;       // 0..2303
  int c = 0;
  #pragma unroll
  for (int cc = 1; cc < 8; ++cc) if (n >= 32*cc*(cc+1)) c = cc;
  int rem = n - 32*c*(c+1);
  int jq = rem / (c + 1);
  int j = 64*c + jq;
  int w = rem - jq*(c+1);
  if (j >= V) return;

  const float4* fb = fbox4 + cls * MAXFV;
  const float*  fa = farea + cls * MAXFV;
  float4 mb = fb[j];
  float  ma = fa[j];
  int i0 = 64*w;
  int i1 = min(i0 + 64, j);
  unsigned long long acc = 0ull;
  #pragma unroll 8
  for (int i = i0; i < i1; ++i) {
    float4 bb = fb[i]; float ba = fa[i];
    float ty=fmaxf(bb.x,mb.x), tx=fmaxf(bb.y,mb.y);
    float by=fminf(bb.z,mb.z), bz=fminf(bb.w,mb.w);
    float w0=fmaxf(by-ty,0.f), w1=fmaxf(bz-tx,0.f);
    float inter=w0*w1;
    float uni=fmaxf(ba+ma-inter, 1e-9f);
    float rhs=0.3f*uni;
    bool kill = inter > rhs + FMARGIN;
    if (!kill && inter > rhs - FMARGIN) {       // rare: exact f64, reference op order
      double4 bd = dbox4s[cls*MAXFV + i];
      double4 md = dbox4s[cls*MAXFV + j];
      double bar=(bd.z-bd.x)*(bd.w-bd.y);
      double dar=(md.z-md.x)*(md.w-md.y);
      double ty_=fmax(bd.x,md.x), tx_=fmax(bd.y,md.y);
      double by_=fmin(bd.z,md.z), bz_=fmin(bd.w,md.w);
      double w0_=fmax(by_-ty_,0.0), w1_=fmax(bz_-tx_,0.0);
      double in_=w0_*w1_;
      double un_=bar+dar-in_;
      kill = in_/fmax(un_,1e-9) > 0.3;
    }
    acc |= (unsigned long long)(kill ? 1 : 0) << (i & 63);
  }
  kw[(size_t)(cls*MAXFV + j)*8 + w] = acc;
}

// ---- K4: greedy bit-scan + kept-row-only output write ----
__global__ __launch_bounds__(256) void scan_kernel(
    float* __restrict__ out,
    const float4* __restrict__ fbox4, const float* __restrict__ sprobg,
    const unsigned long long* __restrict__ kw, const int* __restrict__ vcls)
{
  __shared__ unsigned long long ckill[2][8][256];
  __shared__ unsigned long long keptm[8];
  const int cls = blockIdx.x;
  const int V = vcls[cls];
  if (V > MAXFV) return;                 // sortexport fallback already wrote out
  const int t = threadIdx.x, lane = t & 63, wid = t >> 6;

  unsigned long long ckq[2] = {0ull, 0ull};
  unsigned am = 0;
  #pragma unroll
  for (int q = 0; q < 2; ++q) {
    int j = t + 256*q;
    if (j < V) {
      am |= 1u << q;
      const unsigned long long* src = kw + (size_t)(cls*MAXFV + j)*8;
      int c = wid + 4*q;                 // own chunk = j>>6 (wave-uniform)
      for (int w = 0; w < c; ++w) ckill[q][w][t] = src[w];
      ckq[q] = src[c];
    }
  }

  unsigned km = 0;
  #pragma unroll
  for (int q = 0; q < 2; ++q) {
    if (256*q >= V) break;
    for (int sub = 0; sub < 4; ++sub) {
      const int ch = 4*q + sub;
      if (64*ch >= V) break;
      if (wid == sub) {
        bool a = ((am >> q) & 1u) != 0u;
        unsigned long long m = __ballot(a);
        unsigned long long kept = 0ull;
        while (m) {
          int i = __ffsll(m) - 1;
          unsigned long long bit = 1ull << i;
          kept |= bit; m &= ~bit;
          bool kill = ((ckq[q] >> i) & 1ull) != 0ull;
          m &= ~__ballot(kill);
        }
        am &= ~(1u << q);
        if ((kept >> lane) & 1ull) km |= 1u << q;
        if (lane == 0) keptm[ch] = kept;
      }
      __syncthreads();
      unsigned long long K = keptm[ch];
      #pragma unroll
      for (int q2 = 0; q2 < 2; ++q2) {
        if (256*q2 >= V) break;
        if (((am >> q2) & 1u) && (wid + 4*q2) > ch) {
          if (ckill[q2][ch][t] & K) am &= ~(1u << q2);
        }
      }
    }
  }

  // write ONLY kept rows (prep3 already zeroed the whole output)
  #pragma unroll
  for (int q = 0; q < 2; ++q) {
    int j = t + 256*q;
    if (j < V && ((km >> q) & 1u)) {
      int row = cls*R_N + j;
      float4 b = fbox4[cls*MAXFV + j];
      out[row*5+0]=b.x; out[row*5+1]=b.y; out[row*5+2]=b.z; out[row*5+3]=b.w;
      out[row*5+4]=sprobg[cls*MAXFV + j];
      out[OUT_LBL  + row] = (float)(cls + 1);
      out[OUT_KEEP + row] = 1.f;
    }
  }
}

extern "C" void kernel_launch(void* const* d_in, const int* in_sizes, int n_in,
                              void* d_out, int out_size, void* d_ws, size_t ws_size,
                              hipStream_t stream) {
  const float* rois  = (const float*)d_in[0];
  const float* loc   = (const float*)d_in[1];
  const float* score = (const float*)d_in[2];
  const void*  hp    = d_in[3];
  const void*  wp    = d_in[4];
  float* out = (float*)d_out;

  // ws layout (bytes):
  //   dbox_all f64x4[20*2000] @ 0          1,280,000
  //   prob_t   f64[20*2000]   @ 1,280,000    320,000
  //   fbox4    f32x4[20*512]  @ 1,600,000    163,840
  //   dbox4s   f64x4[20*512]  @ 1,763,840    327,680
  //   farea    f32[20*512]    @ 2,091,520     40,960
  //   sprob    f32[20*512]    @ 2,132,480     40,960
  //   kw       u64[20*512*8]  @ 2,173,440    655,360
  //   vcls     i32[20]        @ 2,828,800         80
  char* wsb = (char*)d_ws;
  double4* dbox_all = (double4*)(wsb + 0);
  double*  prob_t   = (double*)(wsb + 1280000);
  float4*  fbox4    = (float4*)(wsb + 1600000);
  double4* dbox4s   = (double4*)(wsb + 1763840);
  float*   farea    = (float*)(wsb + 2091520);
  float*   sprob    = (float*)(wsb + 2132480);
  unsigned long long* kw = (unsigned long long*)(wsb + 2173440);
  int*     vcls     = (int*)(wsb + 2828800);
  const size_t WS_NEED = 2828880;

  if (ws_size >= WS_NEED) {
    prep3_kernel<<<dim3(168), dim3(256), 0, stream>>>(rois, loc, score, hp, wp,
                                                      dbox_all, prob_t, out);
    sortexport_kernel<<<dim3(NCLS), dim3(256), 0, stream>>>(
        rois, loc, score, hp, wp, out, dbox_all, prob_t,
        fbox4, dbox4s, farea, sprob, vcls, 1);
    build_kernel<<<dim3(NCLS, 9), dim3(256), 0, stream>>>(fbox4, farea, dbox4s, vcls, kw);
    scan_kernel<<<dim3(NCLS), dim3(256), 0, stream>>>(out, fbox4, sprob, kw, vcls);
  } else {
    sortexport_kernel<<<dim3(NCLS), dim3(256), 0, stream>>>(
        rois, loc, score, hp, wp, out, (const double4*)nullptr, (const double*)nullptr,
        (float4*)nullptr, (double4*)nullptr, (float*)nullptr, (float*)nullptr,
        (int*)nullptr, 0);
  }
}